// Round 1
// baseline (872.242 us; speedup 1.0000x reference)
//
#include <hip/hip_runtime.h>
#include <hip/hip_bf16.h>

typedef __attribute__((ext_vector_type(8))) __bf16 bf16x8;
typedef __attribute__((ext_vector_type(4))) float  f32x4;

#define BM 128
#define BN 128
#define BK 32

// ---------------------------------------------------------------------------
// W fp32 -> bf16 conversion (grid-stride, 8 elems/thread/iter)
// ---------------------------------------------------------------------------
__global__ __launch_bounds__(256) void cvt_f32_bf16(
    const float* __restrict__ in, __bf16* __restrict__ out, long n8)
{
    long i = (long)blockIdx.x * blockDim.x + threadIdx.x;
    long stride = (long)gridDim.x * blockDim.x;
    for (; i < n8; i += stride) {
        const f32x4* p = (const f32x4*)(in + i * 8);
        f32x4 a = p[0], b = p[1];
        bf16x8 o;
        o[0] = (__bf16)a[0]; o[1] = (__bf16)a[1];
        o[2] = (__bf16)a[2]; o[3] = (__bf16)a[3];
        o[4] = (__bf16)b[0]; o[5] = (__bf16)b[1];
        o[6] = (__bf16)b[2]; o[7] = (__bf16)b[3];
        *(bf16x8*)(out + i * 8) = o;
    }
}

// ---------------------------------------------------------------------------
// Fused: mid[m][0:16] = x[m,:] @ A^T  (fp32)  AND  Xb[m,:] = bf16(x[m,:])
// One block per row m; 256 threads; each thread handles 8 consecutive k.
// ---------------------------------------------------------------------------
__global__ __launch_bounds__(256) void mid_and_cvt(
    const float* __restrict__ x, const float* __restrict__ A,
    float* __restrict__ mid, __bf16* __restrict__ Xb, int K)
{
    int m = blockIdx.x;
    int tid = threadIdx.x;
    const float* xr = x + (size_t)m * K;

    float acc[16];
#pragma unroll
    for (int r = 0; r < 16; ++r) acc[r] = 0.f;

    int iters = K / 2048;  // 256 threads * 8 elems
    for (int it = 0; it < iters; ++it) {
        int k = it * 2048 + tid * 8;
        f32x4 x0 = *(const f32x4*)(xr + k);
        f32x4 x1 = *(const f32x4*)(xr + k + 4);
        if (Xb) {
            bf16x8 o;
            o[0] = (__bf16)x0[0]; o[1] = (__bf16)x0[1];
            o[2] = (__bf16)x0[2]; o[3] = (__bf16)x0[3];
            o[4] = (__bf16)x1[0]; o[5] = (__bf16)x1[1];
            o[6] = (__bf16)x1[2]; o[7] = (__bf16)x1[3];
            *(bf16x8*)(Xb + (size_t)m * K + k) = o;
        }
#pragma unroll
        for (int r = 0; r < 16; ++r) {
            const f32x4* ap = (const f32x4*)(A + (size_t)r * K + k);
            f32x4 a0 = ap[0], a1 = ap[1];
            acc[r] += x0[0]*a0[0] + x0[1]*a0[1] + x0[2]*a0[2] + x0[3]*a0[3]
                    + x1[0]*a1[0] + x1[1]*a1[1] + x1[2]*a1[2] + x1[3]*a1[3];
        }
    }

    // wave reduce, then cross-wave via LDS
#pragma unroll
    for (int r = 0; r < 16; ++r) {
#pragma unroll
        for (int off = 32; off > 0; off >>= 1)
            acc[r] += __shfl_down(acc[r], off, 64);
    }
    __shared__ float red[4][16];
    int lane = tid & 63, w = tid >> 6;
    if (lane == 0) {
#pragma unroll
        for (int r = 0; r < 16; ++r) red[w][r] = acc[r];
    }
    __syncthreads();
    if (tid < 16) {
        float s = red[0][tid] + red[1][tid] + red[2][tid] + red[3][tid];
        mid[(size_t)m * 16 + tid] = s;
    }
}

// ---------------------------------------------------------------------------
// Main bf16 MFMA NT-GEMM (m97 structure): out = Xb @ Wb^T + 2*mid @ Bl^T
// 128x128 tile, BK=32, 4 waves (2x2), each wave 64x64 = 4x4 MFMA frags,
// global_load_lds width=16, 2 barriers per K-step. XCD-swizzled blockIdx.
// ---------------------------------------------------------------------------
__global__ __launch_bounds__(256) void gemm_lora(
    const __bf16* __restrict__ Xb,   // [M][K]
    const __bf16* __restrict__ Wb,   // [N][K]
    const float*  __restrict__ mid,  // [M][16]
    const float*  __restrict__ Bl,   // [N][16]
    float* __restrict__ out,         // [M][N]
    int M, int N, int K)
{
    __shared__ __bf16 As[BM * BK];
    __shared__ __bf16 Bs[BN * BK];

    int nbx = N / BN;
    int nby = M / BM;
    int nwg = nbx * nby;
    int bid = blockIdx.x;
    // bijective XCD swizzle (nwg % 8 == 0 for this shape)
    int swz = bid;
    if ((nwg & 7) == 0) {
        int cpx = nwg >> 3;
        swz = (bid & 7) * cpx + (bid >> 3);
    }
    int by = swz / nbx, bx = swz % nbx;
    int m0 = by * BM, n0 = bx * BN;

    int tid  = threadIdx.x;
    int lane = tid & 63;
    int w    = tid >> 6;          // wave 0..3
    int wm   = w >> 1, wn = w & 1; // 2x2 wave grid, each 64x64

    f32x4 zero = {0.f, 0.f, 0.f, 0.f};
    f32x4 acc[4][4];
#pragma unroll
    for (int i = 0; i < 4; ++i)
#pragma unroll
        for (int j = 0; j < 4; ++j) acc[i][j] = zero;

    const __bf16* agbase = Xb + (size_t)m0 * K;
    const __bf16* bgbase = Wb + (size_t)n0 * K;

    for (int kt = 0; kt < K; kt += BK) {
        // ---- stage A,B tiles via async global->LDS (16B/lane) ----
#pragma unroll
        for (int r = 0; r < 2; ++r) {
            int c   = r * 256 + tid;       // chunk index, 16B chunks
            int row = c >> 2;
            int kc  = c & 3;
            unsigned ldsoff = (unsigned)(r * 256 + w * 64) * 16; // wave-uniform
            const __bf16* ga = agbase + (size_t)row * K + kt + kc * 8;
            __builtin_amdgcn_global_load_lds(
                (const __attribute__((address_space(1))) void*)ga,
                (__attribute__((address_space(3))) void*)((char*)As + ldsoff),
                16, 0, 0);
            const __bf16* gb = bgbase + (size_t)row * K + kt + kc * 8;
            __builtin_amdgcn_global_load_lds(
                (const __attribute__((address_space(1))) void*)gb,
                (__attribute__((address_space(3))) void*)((char*)Bs + ldsoff),
                16, 0, 0);
        }
        __syncthreads();

        // ---- fragments + MFMA ----
        bf16x8 af[4], bfr[4];
#pragma unroll
        for (int i = 0; i < 4; ++i) {
            int arow = wm * 64 + i * 16 + (lane & 15);
            af[i]  = *(const bf16x8*)(As + arow * BK + (lane >> 4) * 8);
            int brow = wn * 64 + i * 16 + (lane & 15);
            bfr[i] = *(const bf16x8*)(Bs + brow * BK + (lane >> 4) * 8);
        }
#pragma unroll
        for (int i = 0; i < 4; ++i)
#pragma unroll
            for (int j = 0; j < 4; ++j)
                acc[i][j] = __builtin_amdgcn_mfma_f32_16x16x32_bf16(
                    af[i], bfr[j], acc[i][j], 0, 0, 0);
        __syncthreads();
    }

    // ---- epilogue: add 2.0 * mid[row,0:16] . Bl[col,0:16], write fp32 ----
    const float scl = 2.0f;
#pragma unroll
    for (int j = 0; j < 4; ++j) {
        int col = n0 + wn * 64 + j * 16 + (lane & 15);
        const f32x4* bp = (const f32x4*)(Bl + (size_t)col * 16);
        f32x4 b0 = bp[0], b1 = bp[1], b2 = bp[2], b3 = bp[3];
#pragma unroll
        for (int i = 0; i < 4; ++i) {
            int rbase = m0 + wm * 64 + i * 16 + ((lane >> 4) << 2);
#pragma unroll
            for (int q = 0; q < 4; ++q) {
                int row = rbase + q;
                const f32x4* mp = (const f32x4*)(mid + (size_t)row * 16);
                f32x4 mv0 = mp[0], mv1 = mp[1], mv2 = mp[2], mv3 = mp[3];
                float s = mv0[0]*b0[0] + mv0[1]*b0[1] + mv0[2]*b0[2] + mv0[3]*b0[3]
                        + mv1[0]*b1[0] + mv1[1]*b1[1] + mv1[2]*b1[2] + mv1[3]*b1[3]
                        + mv2[0]*b2[0] + mv2[1]*b2[1] + mv2[2]*b2[2] + mv2[3]*b2[3]
                        + mv3[0]*b3[0] + mv3[1]*b3[1] + mv3[2]*b3[2] + mv3[3]*b3[3];
                out[(size_t)row * N + col] = acc[i][j][q] + scl * s;
            }
        }
    }
}

// ---------------------------------------------------------------------------
// Fallback fp32 GEMM (used only if workspace too small for bf16 buffers)
// 64x64 tile, BK=16, 256 threads, 4x4 per thread.
// ---------------------------------------------------------------------------
__global__ __launch_bounds__(256) void gemm_fb(
    const float* __restrict__ X, const float* __restrict__ W,
    const float* __restrict__ mid, const float* __restrict__ Bl,
    float* __restrict__ out, int M, int N, int K)
{
    __shared__ float As[64][16];
    __shared__ float Bs[64][16];
    int nbx = N / 64;
    int bx = blockIdx.x % nbx, by = blockIdx.x / nbx;
    int m0 = by * 64, n0 = bx * 64;
    int tid = threadIdx.x;
    int tr = tid >> 4, tc = tid & 15;

    float acc[4][4] = {};
    for (int kt = 0; kt < K; kt += 16) {
#pragma unroll
        for (int s = 0; s < 4; ++s) {
            int c = s * 256 + tid;
            int row = c >> 4, kk = c & 15;
            As[row][kk] = X[(size_t)(m0 + row) * K + kt + kk];
            Bs[row][kk] = W[(size_t)(n0 + row) * K + kt + kk];
        }
        __syncthreads();
#pragma unroll
        for (int kk = 0; kk < 16; ++kk) {
            float av[4], bv[4];
#pragma unroll
            for (int i = 0; i < 4; ++i) { av[i] = As[tr*4+i][kk]; bv[i] = Bs[tc*4+i][kk]; }
#pragma unroll
            for (int i = 0; i < 4; ++i)
#pragma unroll
                for (int j = 0; j < 4; ++j) acc[i][j] += av[i] * bv[j];
        }
        __syncthreads();
    }
#pragma unroll
    for (int i = 0; i < 4; ++i) {
        int row = m0 + tr * 4 + i;
#pragma unroll
        for (int j = 0; j < 4; ++j) {
            int col = n0 + tc * 4 + j;
            float s = 0.f;
#pragma unroll
            for (int r = 0; r < 16; ++r)
                s += mid[(size_t)row * 16 + r] * Bl[(size_t)col * 16 + r];
            out[(size_t)row * N + col] = acc[i][j] + 2.0f * s;
        }
    }
}

// ---------------------------------------------------------------------------
extern "C" void kernel_launch(void* const* d_in, const int* in_sizes, int n_in,
                              void* d_out, int out_size, void* d_ws, size_t ws_size,
                              hipStream_t stream)
{
    const float* x   = (const float*)d_in[0];
    const float* Wf  = (const float*)d_in[1];
    const float* A   = (const float*)d_in[2];
    const float* Bl  = (const float*)d_in[3];
    float* out = (float*)d_out;

    int D = in_sizes[2] / 16;            // A is [16, D]
    int O = in_sizes[3] / 16;            // B is [O, 16]
    long M = (long)in_sizes[0] / D;      // x is [M, D]
    int K = D, N = O;

    size_t xb_bytes  = (size_t)M * K * 2;
    size_t wb_bytes  = (size_t)N * K * 2;
    size_t mid_bytes = (size_t)M * 16 * 4;

    if (ws_size >= xb_bytes + wb_bytes + mid_bytes) {
        __bf16* Xb  = (__bf16*)d_ws;
        __bf16* Wbb = (__bf16*)((char*)d_ws + xb_bytes);
        float*  mid = (float*)((char*)d_ws + xb_bytes + wb_bytes);

        cvt_f32_bf16<<<2048, 256, 0, stream>>>(Wf, Wbb, (long)N * K / 8);
        mid_and_cvt<<<(int)M, 256, 0, stream>>>(x, A, mid, Xb, K);
        int nwg = (int)(M / BM) * (N / BN);
        gemm_lora<<<nwg, 256, 0, stream>>>(Xb, Wbb, mid, Bl, out, (int)M, N, K);
    } else {
        float* mid = (float*)d_ws;  // needs only 512 KiB
        mid_and_cvt<<<(int)M, 256, 0, stream>>>(x, A, mid, nullptr, K);
        int nwg = (int)(M / 64) * (N / 64);
        gemm_fb<<<nwg, 256, 0, stream>>>(x, Wf, mid, Bl, out, (int)M, N, K);
    }
}

// Round 2
// 398.269 us; speedup vs baseline: 2.1901x; 2.1901x over previous
//
#include <hip/hip_runtime.h>
#include <hip/hip_bf16.h>

typedef __attribute__((ext_vector_type(8))) __bf16 bf16x8;
typedef __attribute__((ext_vector_type(4))) float  f32x4;

// ---------------------------------------------------------------------------
// W fp32 -> bf16 conversion (grid-stride, 8 elems/thread/iter)
// ---------------------------------------------------------------------------
__global__ __launch_bounds__(256) void cvt_f32_bf16(
    const float* __restrict__ in, __bf16* __restrict__ out, long n8)
{
    long i = (long)blockIdx.x * blockDim.x + threadIdx.x;
    long stride = (long)gridDim.x * blockDim.x;
    for (; i < n8; i += stride) {
        const f32x4* p = (const f32x4*)(in + i * 8);
        f32x4 a = p[0], b = p[1];
        bf16x8 o;
        o[0] = (__bf16)a[0]; o[1] = (__bf16)a[1];
        o[2] = (__bf16)a[2]; o[3] = (__bf16)a[3];
        o[4] = (__bf16)b[0]; o[5] = (__bf16)b[1];
        o[6] = (__bf16)b[2]; o[7] = (__bf16)b[3];
        *(bf16x8*)(out + i * 8) = o;
    }
}

// ---------------------------------------------------------------------------
// Fused: mid[m][0:16] = x[m,:] @ A^T  (fp32)  AND  Xb[m,:] = bf16(x[m,:])
// ---------------------------------------------------------------------------
__global__ __launch_bounds__(256) void mid_and_cvt(
    const float* __restrict__ x, const float* __restrict__ A,
    float* __restrict__ mid, __bf16* __restrict__ Xb, int K)
{
    int m = blockIdx.x;
    int tid = threadIdx.x;
    const float* xr = x + (size_t)m * K;

    float acc[16];
#pragma unroll
    for (int r = 0; r < 16; ++r) acc[r] = 0.f;

    int iters = K / 2048;
    for (int it = 0; it < iters; ++it) {
        int k = it * 2048 + tid * 8;
        f32x4 x0 = *(const f32x4*)(xr + k);
        f32x4 x1 = *(const f32x4*)(xr + k + 4);
        if (Xb) {
            bf16x8 o;
            o[0] = (__bf16)x0[0]; o[1] = (__bf16)x0[1];
            o[2] = (__bf16)x0[2]; o[3] = (__bf16)x0[3];
            o[4] = (__bf16)x1[0]; o[5] = (__bf16)x1[1];
            o[6] = (__bf16)x1[2]; o[7] = (__bf16)x1[3];
            *(bf16x8*)(Xb + (size_t)m * K + k) = o;
        }
#pragma unroll
        for (int r = 0; r < 16; ++r) {
            const f32x4* ap = (const f32x4*)(A + (size_t)r * K + k);
            f32x4 a0 = ap[0], a1 = ap[1];
            acc[r] += x0[0]*a0[0] + x0[1]*a0[1] + x0[2]*a0[2] + x0[3]*a0[3]
                    + x1[0]*a1[0] + x1[1]*a1[1] + x1[2]*a1[2] + x1[3]*a1[3];
        }
    }

#pragma unroll
    for (int r = 0; r < 16; ++r) {
#pragma unroll
        for (int off = 32; off > 0; off >>= 1)
            acc[r] += __shfl_down(acc[r], off, 64);
    }
    __shared__ float red[4][16];
    int lane = tid & 63, w = tid >> 6;
    if (lane == 0) {
#pragma unroll
        for (int r = 0; r < 16; ++r) red[w][r] = acc[r];
    }
    __syncthreads();
    if (tid < 16) {
        float s = red[0][tid] + red[1][tid] + red[2][tid] + red[3][tid];
        mid[(size_t)m * 16 + tid] = s;
    }
}

// ---------------------------------------------------------------------------
// 256x256-tile deep-pipelined bf16 MFMA NT-GEMM, 512 threads (8 waves 2x4).
// BK=32. 4 LDS buffers (128 KiB): stage tile t+2 while computing tile t,
// counted vmcnt(4) at tile boundaries (tile t+1 already fully landed).
// LDS XOR chunk-swizzle (T2) via pre-swizzled global source (linear dest for
// global_load_lds) + swizzled ds_read. setprio around MFMA clusters (T5).
// LoRA update folded into accumulator init via one K=32 MFMA over [mid|0],[2B|0].
// ---------------------------------------------------------------------------
#define GL16(g, l) __builtin_amdgcn_global_load_lds( \
    (const __attribute__((address_space(1))) void*)(g), \
    (__attribute__((address_space(3))) void*)(l), 16, 0, 0)

__global__ __launch_bounds__(512, 2) void gemm256(
    const __bf16* __restrict__ Xb,   // [M][K]
    const __bf16* __restrict__ Wb,   // [N][K]
    const float*  __restrict__ mid,  // [M][16]
    const float*  __restrict__ Bl,   // [N][16]
    float* __restrict__ out,         // [M][N]
    int M, int N, int K)
{
    __shared__ __bf16 As[4][256 * 32];   // 4 x 16 KiB
    __shared__ __bf16 Bs[4][256 * 32];   // 4 x 16 KiB  -> 128 KiB total

    const int NT = K >> 5;               // BK = 32

    int nbx = N >> 8, nby = M >> 8, nwg = nbx * nby;
    int bid = blockIdx.x, swz = bid;
    if ((nwg & 7) == 0) { int cpx = nwg >> 3; swz = (bid & 7) * cpx + (bid >> 3); }
    int by = swz / nbx, bx = swz % nbx;
    int m0 = by << 8, n0 = bx << 8;

    int tid = threadIdx.x;
    int lane = tid & 63;
    int w = tid >> 6;            // wave 0..7
    int wm = w >> 2, wn = w & 3; // 2 x 4 wave grid; wave tile = 128 x 64

    // ---- staging source (pre-swizzled global chunk so linear LDS dest works)
    int q0 = tid >> 2;                       // row within 128-row issue
    int c0 = tid & 3;                        // LDS chunk slot this lane fills
    int csrc = c0 ^ ((q0 >> 1) & 3);         // inverse-swizzled source chunk
    const __bf16* sA0 = Xb + (size_t)(m0 + q0) * K + csrc * 8;
    const __bf16* sA1 = sA0 + (size_t)128 * K;
    const __bf16* sB0 = Wb + (size_t)(n0 + q0) * K + csrc * 8;
    const __bf16* sB1 = sB0 + (size_t)128 * K;
    unsigned ldsw = (unsigned)w * 1024;      // wave-uniform LDS byte base

    // ---- swizzled ds_read offsets (chunk ^ f(row); f(row)=((row>>1)&3))
    int chunkSwz = (lane >> 4) ^ ((lane >> 1) & 3);
    unsigned aoff = (unsigned)((wm * 128 + (lane & 15)) * 64 + chunkSwz * 16);
    unsigned boff = (unsigned)((wn * 64  + (lane & 15)) * 64 + chunkSwz * 16);

    // ---- acc init = LoRA contribution: mfma([mid|0], [2*Bl|0]) over K=32 ----
    f32x4 acc[8][4];
    {
        int kh = lane >> 4;  // 0..3; k-halves 0,1 hold rank-16 data, 2,3 zero
        bf16x8 bI[4];
#pragma unroll
        for (int j = 0; j < 4; ++j) {
            bf16x8 v = {};
            if (kh < 2) {
                int col = n0 + wn * 64 + j * 16 + (lane & 15);
                const f32x4* p = (const f32x4*)(Bl + (size_t)col * 16 + kh * 8);
                f32x4 v0 = p[0], v1 = p[1];
                v[0] = (__bf16)(2.0f * v0[0]); v[1] = (__bf16)(2.0f * v0[1]);
                v[2] = (__bf16)(2.0f * v0[2]); v[3] = (__bf16)(2.0f * v0[3]);
                v[4] = (__bf16)(2.0f * v1[0]); v[5] = (__bf16)(2.0f * v1[1]);
                v[6] = (__bf16)(2.0f * v1[2]); v[7] = (__bf16)(2.0f * v1[3]);
            }
            bI[j] = v;
        }
#pragma unroll
        for (int i = 0; i < 8; ++i) {
            bf16x8 aI = {};
            if (kh < 2) {
                int row = m0 + wm * 128 + i * 16 + (lane & 15);
                const f32x4* p = (const f32x4*)(mid + (size_t)row * 16 + kh * 8);
                f32x4 v0 = p[0], v1 = p[1];
                aI[0] = (__bf16)v0[0]; aI[1] = (__bf16)v0[1];
                aI[2] = (__bf16)v0[2]; aI[3] = (__bf16)v0[3];
                aI[4] = (__bf16)v1[0]; aI[5] = (__bf16)v1[1];
                aI[6] = (__bf16)v1[2]; aI[7] = (__bf16)v1[3];
            }
            f32x4 z = {0.f, 0.f, 0.f, 0.f};
#pragma unroll
            for (int j = 0; j < 4; ++j)
                acc[i][j] = __builtin_amdgcn_mfma_f32_16x16x32_bf16(aI, bI[j], z, 0, 0, 0);
        }
    }

    // ---- prologue: stage tiles 0 and 1 ----
    {
        GL16(sA0, (char*)As[0] + ldsw);
        GL16(sA1, (char*)As[0] + 8192 + ldsw);
        GL16(sB0, (char*)Bs[0] + ldsw);
        GL16(sB1, (char*)Bs[0] + 8192 + ldsw);
        GL16(sA0 + 32, (char*)As[1] + ldsw);
        GL16(sA1 + 32, (char*)As[1] + 8192 + ldsw);
        GL16(sB0 + 32, (char*)Bs[1] + ldsw);
        GL16(sB1 + 32, (char*)Bs[1] + 8192 + ldsw);
    }
    asm volatile("s_waitcnt vmcnt(4)" ::: "memory");  // tile 0 landed
    asm volatile("s_barrier" ::: "memory");

    // ---- main K loop: 2 phases/tile ----
    int cur = 0;
    for (int t = 0; t < NT; ++t) {
        const __bf16* bufA = As[cur];
        const __bf16* bufB = Bs[cur];
        bool pf = (t + 2) < NT;
        int pb = (t + 2) & 3;
        size_t koff = (size_t)(t + 2) * 32;

        // ===== phase A: i = 0..3 =====
        bf16x8 af0, af1, af2, af3, bf0, bf1, bf2, bf3;
        af0 = *(const bf16x8*)((const char*)bufA + aoff);
        af1 = *(const bf16x8*)((const char*)bufA + aoff + 1024);
        af2 = *(const bf16x8*)((const char*)bufA + aoff + 2048);
        af3 = *(const bf16x8*)((const char*)bufA + aoff + 3072);
        bf0 = *(const bf16x8*)((const char*)bufB + boff);
        bf1 = *(const bf16x8*)((const char*)bufB + boff + 1024);
        bf2 = *(const bf16x8*)((const char*)bufB + boff + 2048);
        bf3 = *(const bf16x8*)((const char*)bufB + boff + 3072);
        if (pf) {   // stage A-tile of t+2
            GL16(sA0 + koff, (char*)As[pb] + ldsw);
            GL16(sA1 + koff, (char*)As[pb] + 8192 + ldsw);
        }
        asm volatile("s_barrier" ::: "memory");
        asm volatile("s_waitcnt lgkmcnt(0)" ::: "memory");
        __builtin_amdgcn_sched_barrier(0);
        __builtin_amdgcn_s_setprio(1);
        acc[0][0] = __builtin_amdgcn_mfma_f32_16x16x32_bf16(af0, bf0, acc[0][0], 0, 0, 0);
        acc[0][1] = __builtin_amdgcn_mfma_f32_16x16x32_bf16(af0, bf1, acc[0][1], 0, 0, 0);
        acc[0][2] = __builtin_amdgcn_mfma_f32_16x16x32_bf16(af0, bf2, acc[0][2], 0, 0, 0);
        acc[0][3] = __builtin_amdgcn_mfma_f32_16x16x32_bf16(af0, bf3, acc[0][3], 0, 0, 0);
        acc[1][0] = __builtin_amdgcn_mfma_f32_16x16x32_bf16(af1, bf0, acc[1][0], 0, 0, 0);
        acc[1][1] = __builtin_amdgcn_mfma_f32_16x16x32_bf16(af1, bf1, acc[1][1], 0, 0, 0);
        acc[1][2] = __builtin_amdgcn_mfma_f32_16x16x32_bf16(af1, bf2, acc[1][2], 0, 0, 0);
        acc[1][3] = __builtin_amdgcn_mfma_f32_16x16x32_bf16(af1, bf3, acc[1][3], 0, 0, 0);
        acc[2][0] = __builtin_amdgcn_mfma_f32_16x16x32_bf16(af2, bf0, acc[2][0], 0, 0, 0);
        acc[2][1] = __builtin_amdgcn_mfma_f32_16x16x32_bf16(af2, bf1, acc[2][1], 0, 0, 0);
        acc[2][2] = __builtin_amdgcn_mfma_f32_16x16x32_bf16(af2, bf2, acc[2][2], 0, 0, 0);
        acc[2][3] = __builtin_amdgcn_mfma_f32_16x16x32_bf16(af2, bf3, acc[2][3], 0, 0, 0);
        acc[3][0] = __builtin_amdgcn_mfma_f32_16x16x32_bf16(af3, bf0, acc[3][0], 0, 0, 0);
        acc[3][1] = __builtin_amdgcn_mfma_f32_16x16x32_bf16(af3, bf1, acc[3][1], 0, 0, 0);
        acc[3][2] = __builtin_amdgcn_mfma_f32_16x16x32_bf16(af3, bf2, acc[3][2], 0, 0, 0);
        acc[3][3] = __builtin_amdgcn_mfma_f32_16x16x32_bf16(af3, bf3, acc[3][3], 0, 0, 0);
        __builtin_amdgcn_s_setprio(0);
        asm volatile("s_barrier" ::: "memory");

        // ===== phase B: i = 4..7 =====
        af0 = *(const bf16x8*)((const char*)bufA + aoff + 4096);
        af1 = *(const bf16x8*)((const char*)bufA + aoff + 5120);
        af2 = *(const bf16x8*)((const char*)bufA + aoff + 6144);
        af3 = *(const bf16x8*)((const char*)bufA + aoff + 7168);
        if (pf) {   // stage B-tile of t+2
            GL16(sB0 + koff, (char*)Bs[pb] + ldsw);
            GL16(sB1 + koff, (char*)Bs[pb] + 8192 + ldsw);
        }
        asm volatile("s_barrier" ::: "memory");
        asm volatile("s_waitcnt lgkmcnt(0)" ::: "memory");
        __builtin_amdgcn_sched_barrier(0);
        __builtin_amdgcn_s_setprio(1);
        acc[4][0] = __builtin_amdgcn_mfma_f32_16x16x32_bf16(af0, bf0, acc[4][0], 0, 0, 0);
        acc[4][1] = __builtin_amdgcn_mfma_f32_16x16x32_bf16(af0, bf1, acc[4][1], 0, 0, 0);
        acc[4][2] = __builtin_amdgcn_mfma_f32_16x16x32_bf16(af0, bf2, acc[4][2], 0, 0, 0);
        acc[4][3] = __builtin_amdgcn_mfma_f32_16x16x32_bf16(af0, bf3, acc[4][3], 0, 0, 0);
        acc[5][0] = __builtin_amdgcn_mfma_f32_16x16x32_bf16(af1, bf0, acc[5][0], 0, 0, 0);
        acc[5][1] = __builtin_amdgcn_mfma_f32_16x16x32_bf16(af1, bf1, acc[5][1], 0, 0, 0);
        acc[5][2] = __builtin_amdgcn_mfma_f32_16x16x32_bf16(af1, bf2, acc[5][2], 0, 0, 0);
        acc[5][3] = __builtin_amdgcn_mfma_f32_16x16x32_bf16(af1, bf3, acc[5][3], 0, 0, 0);
        acc[6][0] = __builtin_amdgcn_mfma_f32_16x16x32_bf16(af2, bf0, acc[6][0], 0, 0, 0);
        acc[6][1] = __builtin_amdgcn_mfma_f32_16x16x32_bf16(af2, bf1, acc[6][1], 0, 0, 0);
        acc[6][2] = __builtin_amdgcn_mfma_f32_16x16x32_bf16(af2, bf2, acc[6][2], 0, 0, 0);
        acc[6][3] = __builtin_amdgcn_mfma_f32_16x16x32_bf16(af2, bf3, acc[6][3], 0, 0, 0);
        acc[7][0] = __builtin_amdgcn_mfma_f32_16x16x32_bf16(af3, bf0, acc[7][0], 0, 0, 0);
        acc[7][1] = __builtin_amdgcn_mfma_f32_16x16x32_bf16(af3, bf1, acc[7][1], 0, 0, 0);
        acc[7][2] = __builtin_amdgcn_mfma_f32_16x16x32_bf16(af3, bf2, acc[7][2], 0, 0, 0);
        acc[7][3] = __builtin_amdgcn_mfma_f32_16x16x32_bf16(af3, bf3, acc[7][3], 0, 0, 0);
        __builtin_amdgcn_s_setprio(0);
        // counted vmcnt: allow tile t+2's 4 loads in flight; tile t+1 landed
        if (pf) asm volatile("s_waitcnt vmcnt(4)" ::: "memory");
        else    asm volatile("s_waitcnt vmcnt(0)" ::: "memory");
        asm volatile("s_barrier" ::: "memory");

        cur = (cur + 1) & 3;
    }

    // ---- epilogue: pure f32 stores (LoRA already in acc) ----
#pragma unroll
    for (int i = 0; i < 8; ++i) {
        int rbase = m0 + wm * 128 + i * 16 + ((lane >> 4) << 2);
#pragma unroll
        for (int q = 0; q < 4; ++q) {
            float* orow = out + (size_t)(rbase + q) * N;
            int colb = n0 + wn * 64 + (lane & 15);
            orow[colb]      = acc[i][0][q];
            orow[colb + 16] = acc[i][1][q];
            orow[colb + 32] = acc[i][2][q];
            orow[colb + 48] = acc[i][3][q];
        }
    }
}

// ---------------------------------------------------------------------------
// Fallback fp32 GEMM (used only if workspace too small for bf16 buffers)
// ---------------------------------------------------------------------------
__global__ __launch_bounds__(256) void gemm_fb(
    const float* __restrict__ X, const float* __restrict__ W,
    const float* __restrict__ mid, const float* __restrict__ Bl,
    float* __restrict__ out, int M, int N, int K)
{
    __shared__ float As[64][16];
    __shared__ float Bs[64][16];
    int nbx = N / 64;
    int bx = blockIdx.x % nbx, by = blockIdx.x / nbx;
    int m0 = by * 64, n0 = bx * 64;
    int tid = threadIdx.x;
    int tr = tid >> 4, tc = tid & 15;

    float acc[4][4] = {};
    for (int kt = 0; kt < K; kt += 16) {
#pragma unroll
        for (int s = 0; s < 4; ++s) {
            int c = s * 256 + tid;
            int row = c >> 4, kk = c & 15;
            As[row][kk] = X[(size_t)(m0 + row) * K + kt + kk];
            Bs[row][kk] = W[(size_t)(n0 + row) * K + kt + kk];
        }
        __syncthreads();
#pragma unroll
        for (int kk = 0; kk < 16; ++kk) {
            float av[4], bv[4];
#pragma unroll
            for (int i = 0; i < 4; ++i) { av[i] = As[tr*4+i][kk]; bv[i] = Bs[tc*4+i][kk]; }
#pragma unroll
            for (int i = 0; i < 4; ++i)
#pragma unroll
                for (int j = 0; j < 4; ++j) acc[i][j] += av[i] * bv[j];
        }
        __syncthreads();
    }
#pragma unroll
    for (int i = 0; i < 4; ++i) {
        int row = m0 + tr * 4 + i;
#pragma unroll
        for (int j = 0; j < 4; ++j) {
            int col = n0 + tc * 4 + j;
            float s = 0.f;
#pragma unroll
            for (int r = 0; r < 16; ++r)
                s += mid[(size_t)row * 16 + r] * Bl[(size_t)col * 16 + r];
            out[(size_t)row * N + col] = acc[i][j] + 2.0f * s;
        }
    }
}

// ---------------------------------------------------------------------------
extern "C" void kernel_launch(void* const* d_in, const int* in_sizes, int n_in,
                              void* d_out, int out_size, void* d_ws, size_t ws_size,
                              hipStream_t stream)
{
    const float* x   = (const float*)d_in[0];
    const float* Wf  = (const float*)d_in[1];
    const float* A   = (const float*)d_in[2];
    const float* Bl  = (const float*)d_in[3];
    float* out = (float*)d_out;

    int D = in_sizes[2] / 16;            // A is [16, D]
    int O = in_sizes[3] / 16;            // B is [O, 16]
    long M = (long)in_sizes[0] / D;      // x is [M, D]
    int K = D, N = O;

    size_t xb_bytes  = (size_t)M * K * 2;
    size_t wb_bytes  = (size_t)N * K * 2;
    size_t mid_bytes = (size_t)M * 16 * 4;

    bool shapes_ok = (M % 256 == 0) && (N % 256 == 0) && (K % 32 == 0) && (K >= 128);

    if (shapes_ok && ws_size >= xb_bytes + wb_bytes + mid_bytes) {
        __bf16* Xb  = (__bf16*)d_ws;
        __bf16* Wbb = (__bf16*)((char*)d_ws + xb_bytes);
        float*  mid = (float*)((char*)d_ws + xb_bytes + wb_bytes);

        cvt_f32_bf16<<<2048, 256, 0, stream>>>(Wf, Wbb, (long)N * K / 8);
        mid_and_cvt<<<(int)M, 256, 0, stream>>>(x, A, mid, Xb, K);
        int nwg = (int)(M / 256) * (N / 256);
        gemm256<<<nwg, 512, 0, stream>>>(Xb, Wbb, mid, Bl, out, (int)M, N, K);
    } else {
        float* mid = (float*)d_ws;
        mid_and_cvt<<<(int)M, 256, 0, stream>>>(x, A, mid, nullptr, K);
        int nwg = (int)(M / 64) * (N / 64);
        gemm_fb<<<nwg, 256, 0, stream>>>(x, Wf, mid, Bl, out, (int)M, N, K);
    }
}